// Round 1
// baseline (900.579 us; speedup 1.0000x reference)
//
#include <hip/hip_runtime.h>
#include <stdint.h>

typedef unsigned short u16;
typedef __attribute__((ext_vector_type(8))) u16   u16x8;
typedef __attribute__((ext_vector_type(4))) u16   u16x4;
typedef __attribute__((ext_vector_type(8))) __bf16 bf16x8;
typedef __attribute__((ext_vector_type(4))) float  f32x4;

__device__ __forceinline__ u16 f2bf(float f) {
  union { float f; unsigned u; } x; x.f = f;
  unsigned r = x.u + 0x7fffu + ((x.u >> 16) & 1u);   // RNE
  return (u16)(r >> 16);
}
__device__ __forceinline__ float bf2f(u16 h) {
  union { unsigned u; float f; } x; x.u = ((unsigned)h) << 16;
  return x.f;
}
// async global->LDS, 16B per lane; LDS dest = uniform base + lane*16
__device__ __forceinline__ void gload_lds16(const void* g, void* l) {
  __builtin_amdgcn_global_load_lds(
      (__attribute__((address_space(1))) void*)(void*)g,
      (__attribute__((address_space(3))) void*)l, 16, 0, 0);
}
__device__ __forceinline__ bf16x8 ldfrag(const u16* p) {
  return __builtin_bit_cast(bf16x8, *(const u16x8*)p);
}
#define MFMA_BF16(a, b, c) __builtin_amdgcn_mfma_f32_16x16x32_bf16(a, b, c, 0, 0, 0)

// ---------------- elementwise fp32 -> bf16 ----------------
__global__ __launch_bounds__(256) void k_f32_to_bf16(const float* __restrict__ in,
                                                     u16* __restrict__ out, int n) {
  int i = (blockIdx.x * 256 + threadIdx.x) * 4;
  if (i >= n) return;
  float4 v = *(const float4*)(in + i);
  u16x4 o; o.x = f2bf(v.x); o.y = f2bf(v.y); o.z = f2bf(v.z); o.w = f2bf(v.w);
  *(u16x4*)(out + i) = o;
}

// ---------------- transpose fp32 (R x C) -> bf16 (C x R) ----------------
__global__ __launch_bounds__(256) void k_transpose_bf16(const float* __restrict__ in,
                                                        u16* __restrict__ out,
                                                        int R, int C) {
  __shared__ float tile[32][33];
  int c0 = blockIdx.x * 32, r0 = blockIdx.y * 32;
  int tx = threadIdx.x, ty = threadIdx.y;  // block (32,8)
#pragma unroll
  for (int i = 0; i < 32; i += 8)
    tile[ty + i][tx] = in[(size_t)(r0 + ty + i) * C + c0 + tx];
  __syncthreads();
#pragma unroll
  for (int i = 0; i < 32; i += 8)
    out[(size_t)(c0 + ty + i) * R + r0 + tx] = f2bf(tile[tx][ty + i]);
}

// ---------------- QKV GEMM: A(8192x1024) @ Wt(3072x1024)^T, scatter epilogue ----
// Q,K -> [b*16+h][s][d] bf16 ; V -> transposed [b*16+h][d][s] bf16
__global__ __launch_bounds__(256) void k_gemm_qkv(const u16* __restrict__ A,
                                                  const u16* __restrict__ Bt,
                                                  u16* __restrict__ Q,
                                                  u16* __restrict__ Kb,
                                                  u16* __restrict__ Vt) {
  const int K = 1024;
  __shared__ u16 As[128 * 32];
  __shared__ u16 Bs[128 * 32];
  int tid = threadIdx.x;
  int wave = tid >> 6, lane = tid & 63, quad = lane >> 4, l15 = lane & 15;
  int m0 = blockIdx.y * 128, n0 = blockIdx.x * 128;
  int wm = (wave >> 1) * 64, wn = (wave & 1) * 64;
  f32x4 acc[4][4] = {};
  const u16* Ag = A + (size_t)m0 * K;
  const u16* Bg = Bt + (size_t)n0 * K;
  int lr = lane >> 2, lk = (lane & 3) * 8;

  for (int k0 = 0; k0 < K; k0 += 32) {
    __syncthreads();
#pragma unroll
    for (int i = 0; i < 2; i++) {
      int c = wave * 2 + i;
      gload_lds16(Ag + (size_t)(c * 16 + lr) * K + k0 + lk, &As[c * 512]);
      gload_lds16(Bg + (size_t)(c * 16 + lr) * K + k0 + lk, &Bs[c * 512]);
    }
    __syncthreads();
    bf16x8 af[4], bf[4];
#pragma unroll
    for (int mi = 0; mi < 4; mi++) af[mi] = ldfrag(&As[(wm + mi * 16 + l15) * 32 + quad * 8]);
#pragma unroll
    for (int ni = 0; ni < 4; ni++) bf[ni] = ldfrag(&Bs[(wn + ni * 16 + l15) * 32 + quad * 8]);
#pragma unroll
    for (int mi = 0; mi < 4; mi++)
#pragma unroll
      for (int ni = 0; ni < 4; ni++)
        acc[mi][ni] = MFMA_BF16(af[mi], bf[ni], acc[mi][ni]);
  }
  int sec = n0 >> 10;  // uniform per block: 0=q 1=k 2=v
#pragma unroll
  for (int mi = 0; mi < 4; mi++) {
    int rowb = m0 + wm + mi * 16 + quad * 4;
#pragma unroll
    for (int ni = 0; ni < 4; ni++) {
      int col = n0 + wn + ni * 16 + l15;
      int cc = col & 1023, h = cc >> 6, d = cc & 63;
#pragma unroll
      for (int r = 0; r < 4; r++) {
        int rg = rowb + r, b = rg >> 12, s = rg & 4095;
        u16 v = f2bf(acc[mi][ni][r]);
        size_t bh = (size_t)(b * 16 + h);
        if (sec == 0)      Q [(bh * 4096 + s) * 64 + d] = v;
        else if (sec == 1) Kb[(bh * 4096 + s) * 64 + d] = v;
        else               Vt[(bh * 64 + d) * 4096 + s] = v;
      }
    }
  }
}

// ---------------- RMSNorm + RoPE, in place, one 64-lane wave per head-row -------
__global__ __launch_bounds__(256) void k_rms_rope(u16* __restrict__ buf,
                                                  const float* __restrict__ gamma,
                                                  const float* __restrict__ cosb,
                                                  const float* __restrict__ sinb,
                                                  float scale) {
  int rid = blockIdx.x * 4 + (threadIdx.x >> 6);  // row over B*NH*S
  int d = threadIdx.x & 63;
  int s = rid & 4095;
  size_t idx = (size_t)rid * 64 + d;
  float x = bf2f(buf[idx]);
  float ss = x * x;
#pragma unroll
  for (int off = 1; off < 64; off <<= 1) ss += __shfl_xor(ss, off);
  float rms = rsqrtf(ss * (1.0f / 64.0f) + 1e-6f);
  float xn = x * rms * gamma[d];
  float partner = __shfl_xor(xn, 32);
  float rot = (d < 32) ? -partner : partner;
  float o = (xn * cosb[s * 64 + d] + rot * sinb[s * 64 + d]) * scale;
  buf[idx] = f2bf(o);
}

// ---------------- causal flash attention -----------------------------------
// Q,K: [bh][s][d] bf16 ; Vt: [bh][d][s] bf16 ; out: [b][s][h*64+d] bf16
__global__ __launch_bounds__(256) void k_attn(const u16* __restrict__ Qb,
                                              const u16* __restrict__ Kbuf,
                                              const u16* __restrict__ Vtb,
                                              u16* __restrict__ Ob) {
  __shared__ u16 Qs[128 * 64];     // 16 KB, persistent
  __shared__ u16 KPs[128 * 128];   // 32 KB: first 8192 = K tile; later P (4 waves x 32x128)
  __shared__ u16 Vts[64 * 128];    // 16 KB
  int qi = blockIdx.x, bhi = blockIdx.y;
  int tid = threadIdx.x, wave = tid >> 6, lane = tid & 63, quad = lane >> 4, l15 = lane & 15;

  const u16* Qg = Qb + ((size_t)bhi * 4096 + qi * 128) * 64;
  const u16* Kg0 = Kbuf + (size_t)bhi * 4096 * 64;
  const u16* Vg0 = Vtb + (size_t)bhi * 64 * 4096;

  {  // stage Q once (first loop barrier covers completion)
    int lr = lane >> 3, lk = (lane & 7) * 8;
#pragma unroll
    for (int i = 0; i < 4; i++) {
      int c = wave * 4 + i;
      gload_lds16(Qg + (size_t)(c * 8 + lr) * 64 + lk, &Qs[c * 512]);
    }
  }
  f32x4 oacc[2][4] = {};
  float mrow[2][4], lrow[2][4];
#pragma unroll
  for (int mi = 0; mi < 2; mi++)
#pragma unroll
    for (int r = 0; r < 4; r++) { mrow[mi][r] = -1e30f; lrow[mi][r] = 0.f; }

  for (int kj = 0; kj <= qi; kj++) {
    {  // stage K tile + V^T tile
      int lr = lane >> 3, lk = (lane & 7) * 8;
      const u16* Kg = Kg0 + (size_t)kj * 128 * 64;
#pragma unroll
      for (int i = 0; i < 4; i++) {
        int c = wave * 4 + i;
        gload_lds16(Kg + (size_t)(c * 8 + lr) * 64 + lk, &KPs[c * 512]);
      }
      int vr = lane >> 4, vk = l15 * 8;
      const u16* Vg = Vg0 + kj * 128;
#pragma unroll
      for (int i = 0; i < 4; i++) {
        int c = wave * 4 + i;
        gload_lds16(Vg + (size_t)(c * 4 + vr) * 4096 + vk, &Vts[c * 512]);
      }
    }
    __syncthreads();
    // S = Q K^T (q pre-scaled by 1/8)
    f32x4 sa[2][8] = {};
#pragma unroll
    for (int ks = 0; ks < 2; ks++) {
      bf16x8 aq[2];
#pragma unroll
      for (int mi = 0; mi < 2; mi++)
        aq[mi] = ldfrag(&Qs[(wave * 32 + mi * 16 + l15) * 64 + ks * 32 + quad * 8]);
#pragma unroll
      for (int ni = 0; ni < 8; ni++) {
        bf16x8 bk = ldfrag(&KPs[(ni * 16 + l15) * 64 + ks * 32 + quad * 8]);
#pragma unroll
        for (int mi = 0; mi < 2; mi++)
          sa[mi][ni] = MFMA_BF16(aq[mi], bk, sa[mi][ni]);
      }
    }
    __syncthreads();  // all waves done reading K; KPs becomes P space
    if (kj == qi) {
#pragma unroll
      for (int mi = 0; mi < 2; mi++)
#pragma unroll
        for (int ni = 0; ni < 8; ni++)
#pragma unroll
          for (int r = 0; r < 4; r++) {
            int rowi = wave * 32 + mi * 16 + quad * 4 + r;
            int coli = ni * 16 + l15;
            if (coli > rowi) sa[mi][ni][r] = -1e30f;
          }
    }
    u16* Pw = &KPs[wave * 4096];  // 32 rows x 128 cols per wave
#pragma unroll
    for (int mi = 0; mi < 2; mi++) {
#pragma unroll
      for (int r = 0; r < 4; r++) {
        float mx = sa[mi][0][r];
#pragma unroll
        for (int ni = 1; ni < 8; ni++) mx = fmaxf(mx, sa[mi][ni][r]);
#pragma unroll
        for (int off = 1; off < 16; off <<= 1) mx = fmaxf(mx, __shfl_xor(mx, off));
        float mnew = fmaxf(mrow[mi][r], mx);
        float alpha = __expf(mrow[mi][r] - mnew);
        mrow[mi][r] = mnew;
        float rsum = 0.f;
        int prow = mi * 16 + quad * 4 + r;
#pragma unroll
        for (int ni = 0; ni < 8; ni++) {
          float p = __expf(sa[mi][ni][r] - mnew);
          rsum += p;
          Pw[prow * 128 + ni * 16 + l15] = f2bf(p);
        }
#pragma unroll
        for (int off = 1; off < 16; off <<= 1) rsum += __shfl_xor(rsum, off);
        lrow[mi][r] = lrow[mi][r] * alpha + rsum;
#pragma unroll
        for (int oni = 0; oni < 4; oni++) oacc[mi][oni][r] *= alpha;
      }
    }
    // O += P V   (P: A-layout from own LDS region; V^T: B^T layout)
#pragma unroll
    for (int ks = 0; ks < 4; ks++) {
      bf16x8 ap[2];
#pragma unroll
      for (int mi = 0; mi < 2; mi++)
        ap[mi] = ldfrag(&Pw[(mi * 16 + l15) * 128 + ks * 32 + quad * 8]);
#pragma unroll
      for (int oni = 0; oni < 4; oni++) {
        bf16x8 bv = ldfrag(&Vts[(oni * 16 + l15) * 128 + ks * 32 + quad * 8]);
#pragma unroll
        for (int mi = 0; mi < 2; mi++)
          oacc[mi][oni] = MFMA_BF16(ap[mi], bv, oacc[mi][oni]);
      }
    }
    __syncthreads();  // protect KPs/Vts before next stage
  }
  int b = bhi >> 4, h = bhi & 15;
#pragma unroll
  for (int mi = 0; mi < 2; mi++)
#pragma unroll
    for (int oni = 0; oni < 4; oni++)
#pragma unroll
      for (int r = 0; r < 4; r++) {
        float v = oacc[mi][oni][r] / lrow[mi][r];
        int srow = qi * 128 + wave * 32 + mi * 16 + quad * 4 + r;
        int d = oni * 16 + l15;
        Ob[((size_t)(b * 4096 + srow)) * 1024 + h * 64 + d] = f2bf(v);
      }
}

// ---------------- out GEMM: A(8192x1024) @ Wot(1024x1024)^T -> fp32 ----------
__global__ __launch_bounds__(256) void k_gemm_out(const u16* __restrict__ A,
                                                  const u16* __restrict__ Bt,
                                                  float* __restrict__ C) {
  const int K = 1024, N = 1024;
  __shared__ u16 As[128 * 32];
  __shared__ u16 Bs[128 * 32];
  int tid = threadIdx.x;
  int wave = tid >> 6, lane = tid & 63, quad = lane >> 4, l15 = lane & 15;
  int m0 = blockIdx.y * 128, n0 = blockIdx.x * 128;
  int wm = (wave >> 1) * 64, wn = (wave & 1) * 64;
  f32x4 acc[4][4] = {};
  const u16* Ag = A + (size_t)m0 * K;
  const u16* Bg = Bt + (size_t)n0 * K;
  int lr = lane >> 2, lk = (lane & 3) * 8;

  for (int k0 = 0; k0 < K; k0 += 32) {
    __syncthreads();
#pragma unroll
    for (int i = 0; i < 2; i++) {
      int c = wave * 2 + i;
      gload_lds16(Ag + (size_t)(c * 16 + lr) * K + k0 + lk, &As[c * 512]);
      gload_lds16(Bg + (size_t)(c * 16 + lr) * K + k0 + lk, &Bs[c * 512]);
    }
    __syncthreads();
    bf16x8 af[4], bf[4];
#pragma unroll
    for (int mi = 0; mi < 4; mi++) af[mi] = ldfrag(&As[(wm + mi * 16 + l15) * 32 + quad * 8]);
#pragma unroll
    for (int ni = 0; ni < 4; ni++) bf[ni] = ldfrag(&Bs[(wn + ni * 16 + l15) * 32 + quad * 8]);
#pragma unroll
    for (int mi = 0; mi < 4; mi++)
#pragma unroll
      for (int ni = 0; ni < 4; ni++)
        acc[mi][ni] = MFMA_BF16(af[mi], bf[ni], acc[mi][ni]);
  }
#pragma unroll
  for (int mi = 0; mi < 4; mi++) {
    int rowb = m0 + wm + mi * 16 + quad * 4;
#pragma unroll
    for (int ni = 0; ni < 4; ni++) {
      int col = n0 + wn + ni * 16 + l15;
#pragma unroll
      for (int r = 0; r < 4; r++)
        C[(size_t)(rowb + r) * N + col] = acc[mi][ni][r];
    }
  }
}

extern "C" void kernel_launch(void* const* d_in, const int* in_sizes, int n_in,
                              void* d_out, int out_size, void* d_ws, size_t ws_size,
                              hipStream_t stream) {
  (void)in_sizes; (void)n_in; (void)out_size; (void)ws_size;
  const float* hs   = (const float*)d_in[0];  // (2,4096,1024)
  const float* cosb = (const float*)d_in[1];  // (1,4096,64)
  const float* sinb = (const float*)d_in[2];
  const float* wqkv = (const float*)d_in[3];  // (1024,3072)
  const float* wo   = (const float*)d_in[4];  // (1024,1024)
  const float* gq   = (const float*)d_in[5];
  const float* gk   = (const float*)d_in[6];
  float* out = (float*)d_out;

  char* ws = (char*)d_ws;
  u16* Xb    = (u16*)(ws);              // 16,777,216 B
  u16* Wqkvt = (u16*)(ws + 16777216);   //  6,291,456 B
  u16* Wot   = (u16*)(ws + 23068672);   //  2,097,152 B
  u16* Qb    = (u16*)(ws + 25165824);   // 16,777,216 B
  u16* Kb    = (u16*)(ws + 41943040);   // 16,777,216 B
  u16* Vtb   = (u16*)(ws + 58720256);   // 16,777,216 B
  u16* Ab    = (u16*)(ws + 75497472);   // 16,777,216 B  (total ~92.3 MB)

  k_f32_to_bf16<<<8192, 256, 0, stream>>>(hs, Xb, 8388608);
  k_transpose_bf16<<<dim3(96, 32), dim3(32, 8), 0, stream>>>(wqkv, Wqkvt, 1024, 3072);
  k_transpose_bf16<<<dim3(32, 32), dim3(32, 8), 0, stream>>>(wo, Wot, 1024, 1024);
  k_gemm_qkv<<<dim3(24, 64), 256, 0, stream>>>(Xb, Wqkvt, Qb, Kb, Vtb);
  k_rms_rope<<<32768, 256, 0, stream>>>(Qb, gq, cosb, sinb, 0.125f);
  k_rms_rope<<<32768, 256, 0, stream>>>(Kb, gk, cosb, sinb, 1.0f);
  k_attn<<<dim3(32, 32), 256, 0, stream>>>(Qb, Kb, Vtb, Ab);
  k_gemm_out<<<dim3(8, 64), 256, 0, stream>>>(Ab, Wot, out);
}

// Round 2
// 799.517 us; speedup vs baseline: 1.1264x; 1.1264x over previous
//
#include <hip/hip_runtime.h>
#include <stdint.h>

typedef unsigned short u16;
typedef __attribute__((ext_vector_type(8))) u16   u16x8;
typedef __attribute__((ext_vector_type(4))) u16   u16x4;
typedef __attribute__((ext_vector_type(8))) __bf16 bf16x8;
typedef __attribute__((ext_vector_type(4))) float  f32x4;

__device__ __forceinline__ u16 f2bf(float f) {
  union { float f; unsigned u; } x; x.f = f;
  unsigned r = x.u + 0x7fffu + ((x.u >> 16) & 1u);   // RNE
  return (u16)(r >> 16);
}
__device__ __forceinline__ float bf2f(u16 h) {
  union { unsigned u; float f; } x; x.u = ((unsigned)h) << 16;
  return x.f;
}
__device__ __forceinline__ float fexp2(float x) {
#if __has_builtin(__builtin_amdgcn_exp2f)
  return __builtin_amdgcn_exp2f(x);
#else
  return __expf(x * 0.69314718055994531f);
#endif
}
// async global->LDS, 16B per lane; LDS dest = uniform base + lane*16
__device__ __forceinline__ void gload_lds16(const void* g, void* l) {
  __builtin_amdgcn_global_load_lds(
      (__attribute__((address_space(1))) void*)(void*)g,
      (__attribute__((address_space(3))) void*)l, 16, 0, 0);
}
__device__ __forceinline__ bf16x8 ldfrag(const u16* p) {
  return __builtin_bit_cast(bf16x8, *(const u16x8*)p);
}
#define MFMA_BF16(a, b, c) __builtin_amdgcn_mfma_f32_16x16x32_bf16(a, b, c, 0, 0, 0)

// ---------------- elementwise fp32 -> bf16 ----------------
__global__ __launch_bounds__(256) void k_f32_to_bf16(const float* __restrict__ in,
                                                     u16* __restrict__ out, int n) {
  int i = (blockIdx.x * 256 + threadIdx.x) * 4;
  if (i >= n) return;
  float4 v = *(const float4*)(in + i);
  u16x4 o; o.x = f2bf(v.x); o.y = f2bf(v.y); o.z = f2bf(v.z); o.w = f2bf(v.w);
  *(u16x4*)(out + i) = o;
}

// ---------------- transpose fp32 (R x C) -> bf16 (C x R) ----------------
__global__ __launch_bounds__(256) void k_transpose_bf16(const float* __restrict__ in,
                                                        u16* __restrict__ out,
                                                        int R, int C) {
  __shared__ float tile[32][33];
  int c0 = blockIdx.x * 32, r0 = blockIdx.y * 32;
  int tx = threadIdx.x, ty = threadIdx.y;  // block (32,8)
#pragma unroll
  for (int i = 0; i < 32; i += 8)
    tile[ty + i][tx] = in[(size_t)(r0 + ty + i) * C + c0 + tx];
  __syncthreads();
#pragma unroll
  for (int i = 0; i < 32; i += 8)
    out[(size_t)(c0 + ty + i) * R + r0 + tx] = f2bf(tile[tx][ty + i]);
}

// ---------------- QKV GEMM: A(8192x1024) @ Wt(3072x1024)^T, scatter epilogue ----
// Q,K -> [b*16+h][s][d] bf16 ; V -> transposed [b*16+h][d][s] bf16
__global__ __launch_bounds__(256) void k_gemm_qkv(const u16* __restrict__ A,
                                                  const u16* __restrict__ Bt,
                                                  u16* __restrict__ Q,
                                                  u16* __restrict__ Kb,
                                                  u16* __restrict__ Vt) {
  const int K = 1024;
  __shared__ u16 As[128 * 32];
  __shared__ u16 Bs[128 * 32];
  int tid = threadIdx.x;
  int wave = tid >> 6, lane = tid & 63, quad = lane >> 4, l15 = lane & 15;
  int m0 = blockIdx.y * 128, n0 = blockIdx.x * 128;
  int wm = (wave >> 1) * 64, wn = (wave & 1) * 64;
  f32x4 acc[4][4] = {};
  const u16* Ag = A + (size_t)m0 * K;
  const u16* Bg = Bt + (size_t)n0 * K;
  int lr = lane >> 2, lk = (lane & 3) * 8;

  for (int k0 = 0; k0 < K; k0 += 32) {
    __syncthreads();
#pragma unroll
    for (int i = 0; i < 2; i++) {
      int c = wave * 2 + i;
      gload_lds16(Ag + (size_t)(c * 16 + lr) * K + k0 + lk, &As[c * 512]);
      gload_lds16(Bg + (size_t)(c * 16 + lr) * K + k0 + lk, &Bs[c * 512]);
    }
    __syncthreads();
    bf16x8 af[4], bf[4];
#pragma unroll
    for (int mi = 0; mi < 4; mi++) af[mi] = ldfrag(&As[(wm + mi * 16 + l15) * 32 + quad * 8]);
#pragma unroll
    for (int ni = 0; ni < 4; ni++) bf[ni] = ldfrag(&Bs[(wn + ni * 16 + l15) * 32 + quad * 8]);
#pragma unroll
    for (int mi = 0; mi < 4; mi++)
#pragma unroll
      for (int ni = 0; ni < 4; ni++)
        acc[mi][ni] = MFMA_BF16(af[mi], bf[ni], acc[mi][ni]);
  }
  int sec = n0 >> 10;  // uniform per block: 0=q 1=k 2=v
#pragma unroll
  for (int mi = 0; mi < 4; mi++) {
    int rowb = m0 + wm + mi * 16 + quad * 4;
#pragma unroll
    for (int ni = 0; ni < 4; ni++) {
      int col = n0 + wn + ni * 16 + l15;
      int cc = col & 1023, h = cc >> 6, d = cc & 63;
#pragma unroll
      for (int r = 0; r < 4; r++) {
        int rg = rowb + r, b = rg >> 12, s = rg & 4095;
        u16 v = f2bf(acc[mi][ni][r]);
        size_t bh = (size_t)(b * 16 + h);
        if (sec == 0)      Q [(bh * 4096 + s) * 64 + d] = v;
        else if (sec == 1) Kb[(bh * 4096 + s) * 64 + d] = v;
        else               Vt[(bh * 64 + d) * 4096 + s] = v;
      }
    }
  }
}

// ---------------- RMSNorm + RoPE, in place, one 64-lane wave per head-row -------
__global__ __launch_bounds__(256) void k_rms_rope(u16* __restrict__ buf,
                                                  const float* __restrict__ gamma,
                                                  const float* __restrict__ cosb,
                                                  const float* __restrict__ sinb,
                                                  float scale) {
  int rid = blockIdx.x * 4 + (threadIdx.x >> 6);  // row over B*NH*S
  int d = threadIdx.x & 63;
  int s = rid & 4095;
  size_t idx = (size_t)rid * 64 + d;
  float x = bf2f(buf[idx]);
  float ss = x * x;
#pragma unroll
  for (int off = 1; off < 64; off <<= 1) ss += __shfl_xor(ss, off);
  float rms = rsqrtf(ss * (1.0f / 64.0f) + 1e-6f);
  float xn = x * rms * gamma[d];
  float partner = __shfl_xor(xn, 32);
  float rot = (d < 32) ? -partner : partner;
  float o = (xn * cosb[s * 64 + d] + rot * sinb[s * 64 + d]) * scale;
  buf[idx] = f2bf(o);
}

// ---------------- causal flash attention -----------------------------------
// Q,K: [bh][s][d] bf16 ; Vt: [bh][d][s] bf16 ; out: [b][s][h*64+d] bf16
// Q frags live in registers (loop-invariant). K/Vt/P in LDS with 16B-chunk
// XOR swizzle (slot = chunk ^ row) -> all ds_read_b128 <=2-way conflicts.
// Heavy-first schedule: qi = 31 - blockIdx.x (LPT packing of causal triangle).
__global__ __launch_bounds__(256) void k_attn(const u16* __restrict__ Qb,
                                              const u16* __restrict__ Kbuf,
                                              const u16* __restrict__ Vtb,
                                              u16* __restrict__ Ob) {
  __shared__ u16 Ks[128 * 64];     // 16 KB, rows of 8 chunks, swizzled
  __shared__ u16 Vts[64 * 128];    // 16 KB, rows of 16 chunks, swizzled
  __shared__ u16 Ps[4 * 32 * 128]; // 32 KB, wave-private 32x128, swizzled
  int qi = 31 - blockIdx.x, bhi = blockIdx.y;
  int tid = threadIdx.x, wave = tid >> 6, lane = tid & 63, quad = lane >> 4, l15 = lane & 15;

  const u16* Qg = Qb + ((size_t)bhi * 4096 + qi * 128) * 64;
  const u16* Kg0 = Kbuf + (size_t)bhi * 4096 * 64;
  const u16* Vg0 = Vtb + (size_t)bhi * 64 * 4096;
  u16* Pw = &Ps[wave * 4096];

  // Q fragments in registers, loop-invariant: aq[mi][ks]
  bf16x8 aq[2][2];
#pragma unroll
  for (int mi = 0; mi < 2; mi++)
#pragma unroll
    for (int ks = 0; ks < 2; ks++)
      aq[mi][ks] = ldfrag(Qg + (size_t)(wave * 32 + mi * 16 + l15) * 64 + ks * 32 + quad * 8);

  f32x4 oacc[2][4] = {};
  float mrow[2][4], lrow[2][4];
#pragma unroll
  for (int mi = 0; mi < 2; mi++)
#pragma unroll
    for (int r = 0; r < 4; r++) { mrow[mi][r] = -1e30f; lrow[mi][r] = 0.f; }

  int klr = lane >> 3, klc = lane & 7;   // K staging: row-in-group, chunk slot
  for (int kj = 0; kj <= qi; kj++) {
    __syncthreads();  // prior iter's K/V reads complete
    {  // stage K tile (swizzled: slot s holds global chunk s^row&7)
      const u16* Kg = Kg0 + (size_t)kj * 128 * 64;
#pragma unroll
      for (int i = 0; i < 4; i++) {
        int c = wave * 4 + i;
        gload_lds16(Kg + (size_t)(c * 8 + klr) * 64 + (klc ^ klr) * 8, &Ks[c * 512]);
      }
      const u16* Vg = Vg0 + kj * 128;
#pragma unroll
      for (int i = 0; i < 4; i++) {
        int c = wave * 4 + i;
        int vr = c * 4 + quad;
        gload_lds16(Vg + (size_t)vr * 4096 + (l15 ^ (vr & 15)) * 8, &Vts[c * 512]);
      }
    }
    __syncthreads();  // staging visible
    // S = Q K^T (q pre-scaled by log2e/8 -> base-2 domain)
    f32x4 sa[2][8] = {};
#pragma unroll
    for (int ks = 0; ks < 2; ks++) {
#pragma unroll
      for (int nb = 0; nb < 8; nb++) {
        bf16x8 bk = ldfrag(&Ks[(nb * 16 + l15) * 64 + (((ks * 4 + quad) ^ (l15 & 7)) << 3)]);
#pragma unroll
        for (int mi = 0; mi < 2; mi++)
          sa[mi][nb] = MFMA_BF16(aq[mi][ks], bk, sa[mi][nb]);
      }
    }
    if (kj == qi) {  // causal mask on diagonal tile (local coords)
#pragma unroll
      for (int mi = 0; mi < 2; mi++)
#pragma unroll
        for (int nb = 0; nb < 8; nb++)
#pragma unroll
          for (int r = 0; r < 4; r++) {
            int rowi = wave * 32 + mi * 16 + quad * 4 + r;
            int coli = nb * 16 + l15;
            if (coli > rowi) sa[mi][nb][r] = -1e30f;
          }
    }
    // online softmax (base-2) + P write (wave-private LDS, swizzled)
#pragma unroll
    for (int mi = 0; mi < 2; mi++) {
#pragma unroll
      for (int r = 0; r < 4; r++) {
        float mx = sa[mi][0][r];
#pragma unroll
        for (int nb = 1; nb < 8; nb++) mx = fmaxf(mx, sa[mi][nb][r]);
#pragma unroll
        for (int off = 1; off < 16; off <<= 1) mx = fmaxf(mx, __shfl_xor(mx, off));
        float mnew = fmaxf(mrow[mi][r], mx);
        float alpha = fexp2(mrow[mi][r] - mnew);
        mrow[mi][r] = mnew;
        int prow = mi * 16 + quad * 4 + r;
        float rsum = 0.f;
#pragma unroll
        for (int nb = 0; nb < 8; nb++) {
          float p = fexp2(sa[mi][nb][r] - mnew);
          rsum += p;
          int slot = (nb * 2 + (l15 >> 3)) ^ (prow & 15);
          Pw[prow * 128 + slot * 8 + (l15 & 7)] = f2bf(p);
        }
#pragma unroll
        for (int off = 1; off < 16; off <<= 1) rsum += __shfl_xor(rsum, off);
        lrow[mi][r] = lrow[mi][r] * alpha + rsum;
#pragma unroll
        for (int oni = 0; oni < 4; oni++) oacc[mi][oni][r] *= alpha;
      }
    }
    // O += P V  (A=P from wave-private LDS, B=V^T; both swizzle-read)
#pragma unroll
    for (int ks = 0; ks < 4; ks++) {
      bf16x8 ap[2];
#pragma unroll
      for (int mi = 0; mi < 2; mi++)
        ap[mi] = ldfrag(&Pw[(mi * 16 + l15) * 128 + (((ks * 4 + quad) ^ l15) << 3)]);
#pragma unroll
      for (int oni = 0; oni < 4; oni++) {
        bf16x8 bv = ldfrag(&Vts[(oni * 16 + l15) * 128 + (((ks * 4 + quad) ^ l15) << 3)]);
#pragma unroll
        for (int mi = 0; mi < 2; mi++)
          oacc[mi][oni] = MFMA_BF16(ap[mi], bv, oacc[mi][oni]);
      }
    }
  }
  int b = bhi >> 4, h = bhi & 15;
#pragma unroll
  for (int mi = 0; mi < 2; mi++)
#pragma unroll
    for (int oni = 0; oni < 4; oni++)
#pragma unroll
      for (int r = 0; r < 4; r++) {
        float v = oacc[mi][oni][r] / lrow[mi][r];
        int srow = qi * 128 + wave * 32 + mi * 16 + quad * 4 + r;
        int d = oni * 16 + l15;
        Ob[((size_t)(b * 4096 + srow)) * 1024 + h * 64 + d] = f2bf(v);
      }
}

// ---------------- out GEMM: A(8192x1024) @ Wot(1024x1024)^T -> fp32 ----------
__global__ __launch_bounds__(256) void k_gemm_out(const u16* __restrict__ A,
                                                  const u16* __restrict__ Bt,
                                                  float* __restrict__ C) {
  const int K = 1024, N = 1024;
  __shared__ u16 As[128 * 32];
  __shared__ u16 Bs[128 * 32];
  int tid = threadIdx.x;
  int wave = tid >> 6, lane = tid & 63, quad = lane >> 4, l15 = lane & 15;
  int m0 = blockIdx.y * 128, n0 = blockIdx.x * 128;
  int wm = (wave >> 1) * 64, wn = (wave & 1) * 64;
  f32x4 acc[4][4] = {};
  const u16* Ag = A + (size_t)m0 * K;
  const u16* Bg = Bt + (size_t)n0 * K;
  int lr = lane >> 2, lk = (lane & 3) * 8;

  for (int k0 = 0; k0 < K; k0 += 32) {
    __syncthreads();
#pragma unroll
    for (int i = 0; i < 2; i++) {
      int c = wave * 2 + i;
      gload_lds16(Ag + (size_t)(c * 16 + lr) * K + k0 + lk, &As[c * 512]);
      gload_lds16(Bg + (size_t)(c * 16 + lr) * K + k0 + lk, &Bs[c * 512]);
    }
    __syncthreads();
    bf16x8 af[4], bf[4];
#pragma unroll
    for (int mi = 0; mi < 4; mi++) af[mi] = ldfrag(&As[(wm + mi * 16 + l15) * 32 + quad * 8]);
#pragma unroll
    for (int ni = 0; ni < 4; ni++) bf[ni] = ldfrag(&Bs[(wn + ni * 16 + l15) * 32 + quad * 8]);
#pragma unroll
    for (int mi = 0; mi < 4; mi++)
#pragma unroll
      for (int ni = 0; ni < 4; ni++)
        acc[mi][ni] = MFMA_BF16(af[mi], bf[ni], acc[mi][ni]);
  }
#pragma unroll
  for (int mi = 0; mi < 4; mi++) {
    int rowb = m0 + wm + mi * 16 + quad * 4;
#pragma unroll
    for (int ni = 0; ni < 4; ni++) {
      int col = n0 + wn + ni * 16 + l15;
#pragma unroll
      for (int r = 0; r < 4; r++)
        C[(size_t)(rowb + r) * N + col] = acc[mi][ni][r];
    }
  }
}

extern "C" void kernel_launch(void* const* d_in, const int* in_sizes, int n_in,
                              void* d_out, int out_size, void* d_ws, size_t ws_size,
                              hipStream_t stream) {
  (void)in_sizes; (void)n_in; (void)out_size; (void)ws_size;
  const float* hs   = (const float*)d_in[0];  // (2,4096,1024)
  const float* cosb = (const float*)d_in[1];  // (1,4096,64)
  const float* sinb = (const float*)d_in[2];
  const float* wqkv = (const float*)d_in[3];  // (1024,3072)
  const float* wo   = (const float*)d_in[4];  // (1024,1024)
  const float* gq   = (const float*)d_in[5];
  const float* gk   = (const float*)d_in[6];
  float* out = (float*)d_out;

  char* ws = (char*)d_ws;
  u16* Xb    = (u16*)(ws);              // 16,777,216 B
  u16* Wqkvt = (u16*)(ws + 16777216);   //  6,291,456 B
  u16* Wot   = (u16*)(ws + 23068672);   //  2,097,152 B
  u16* Qb    = (u16*)(ws + 25165824);   // 16,777,216 B
  u16* Kb    = (u16*)(ws + 41943040);   // 16,777,216 B
  u16* Vtb   = (u16*)(ws + 58720256);   // 16,777,216 B
  u16* Ab    = (u16*)(ws + 75497472);   // 16,777,216 B  (total ~92.3 MB)

  k_f32_to_bf16<<<8192, 256, 0, stream>>>(hs, Xb, 8388608);
  k_transpose_bf16<<<dim3(96, 32), dim3(32, 8), 0, stream>>>(wqkv, Wqkvt, 1024, 3072);
  k_transpose_bf16<<<dim3(32, 32), dim3(32, 8), 0, stream>>>(wo, Wot, 1024, 1024);
  k_gemm_qkv<<<dim3(24, 64), 256, 0, stream>>>(Xb, Wqkvt, Qb, Kb, Vtb);
  // Q scaled by 1/sqrt(hd) * log2(e): softmax runs in base-2 domain
  k_rms_rope<<<32768, 256, 0, stream>>>(Qb, gq, cosb, sinb, 0.18033688011112042f);
  k_rms_rope<<<32768, 256, 0, stream>>>(Kb, gk, cosb, sinb, 1.0f);
  k_attn<<<dim3(32, 32), 256, 0, stream>>>(Qb, Kb, Vtb, Ab);
  k_gemm_out<<<dim3(8, 64), 256, 0, stream>>>(Ab, Wot, out);
}

// Round 3
// 501.706 us; speedup vs baseline: 1.7950x; 1.5936x over previous
//
#include <hip/hip_runtime.h>
#include <stdint.h>

typedef unsigned short u16;
typedef __attribute__((ext_vector_type(8))) u16   u16x8;
typedef __attribute__((ext_vector_type(4))) u16   u16x4;
typedef __attribute__((ext_vector_type(8))) __bf16 bf16x8;
typedef __attribute__((ext_vector_type(4))) float  f32x4;

__device__ __forceinline__ u16 f2bf(float f) {
  union { float f; unsigned u; } x; x.f = f;
  unsigned r = x.u + 0x7fffu + ((x.u >> 16) & 1u);   // RNE
  return (u16)(r >> 16);
}
__device__ __forceinline__ float bf2f(u16 h) {
  union { unsigned u; float f; } x; x.u = ((unsigned)h) << 16;
  return x.f;
}
__device__ __forceinline__ float fexp2(float x) {
#if __has_builtin(__builtin_amdgcn_exp2f)
  return __builtin_amdgcn_exp2f(x);
#else
  return __expf(x * 0.69314718055994531f);
#endif
}
// async global->LDS, 16B per lane; LDS dest = uniform base + lane*16
__device__ __forceinline__ void gload_lds16(const void* g, void* l) {
  __builtin_amdgcn_global_load_lds(
      (__attribute__((address_space(1))) void*)(void*)g,
      (__attribute__((address_space(3))) void*)l, 16, 0, 0);
}
__device__ __forceinline__ bf16x8 ldfrag(const u16* p) {
  return __builtin_bit_cast(bf16x8, *(const u16x8*)p);
}
#define MFMA_BF16(a, b, c) __builtin_amdgcn_mfma_f32_16x16x32_bf16(a, b, c, 0, 0, 0)

// ---------------- elementwise fp32 -> bf16 ----------------
__global__ __launch_bounds__(256) void k_f32_to_bf16(const float* __restrict__ in,
                                                     u16* __restrict__ out, int n) {
  int i = (blockIdx.x * 256 + threadIdx.x) * 4;
  if (i >= n) return;
  float4 v = *(const float4*)(in + i);
  u16x4 o; o.x = f2bf(v.x); o.y = f2bf(v.y); o.z = f2bf(v.z); o.w = f2bf(v.w);
  *(u16x4*)(out + i) = o;
}

// ---------------- transpose fp32 (R x C) -> bf16 (C x R) ----------------
__global__ __launch_bounds__(256) void k_transpose_bf16(const float* __restrict__ in,
                                                        u16* __restrict__ out,
                                                        int R, int C) {
  __shared__ float tile[32][33];
  int c0 = blockIdx.x * 32, r0 = blockIdx.y * 32;
  int tx = threadIdx.x, ty = threadIdx.y;  // block (32,8)
#pragma unroll
  for (int i = 0; i < 32; i += 8)
    tile[ty + i][tx] = in[(size_t)(r0 + ty + i) * C + c0 + tx];
  __syncthreads();
#pragma unroll
  for (int i = 0; i < 32; i += 8)
    out[(size_t)(c0 + ty + i) * R + r0 + tx] = f2bf(tile[tx][ty + i]);
}

// ---------------- QKV GEMM: A(8192x1024) @ Wt(3072x1024)^T, scatter epilogue ----
// Q,K -> [b*16+h][s][d] bf16 ; V -> transposed [b*16+h][d][s] bf16
__global__ __launch_bounds__(256) void k_gemm_qkv(const u16* __restrict__ A,
                                                  const u16* __restrict__ Bt,
                                                  u16* __restrict__ Q,
                                                  u16* __restrict__ Kb,
                                                  u16* __restrict__ Vt) {
  const int K = 1024;
  __shared__ u16 As[128 * 32];
  __shared__ u16 Bs[128 * 32];
  int tid = threadIdx.x;
  int wave = tid >> 6, lane = tid & 63, quad = lane >> 4, l15 = lane & 15;
  int m0 = blockIdx.y * 128, n0 = blockIdx.x * 128;
  int wm = (wave >> 1) * 64, wn = (wave & 1) * 64;
  f32x4 acc[4][4] = {};
  const u16* Ag = A + (size_t)m0 * K;
  const u16* Bg = Bt + (size_t)n0 * K;
  int lr = lane >> 2, lk = (lane & 3) * 8;

  for (int k0 = 0; k0 < K; k0 += 32) {
    __syncthreads();
#pragma unroll
    for (int i = 0; i < 2; i++) {
      int c = wave * 2 + i;
      gload_lds16(Ag + (size_t)(c * 16 + lr) * K + k0 + lk, &As[c * 512]);
      gload_lds16(Bg + (size_t)(c * 16 + lr) * K + k0 + lk, &Bs[c * 512]);
    }
    __syncthreads();
    bf16x8 af[4], bf[4];
#pragma unroll
    for (int mi = 0; mi < 4; mi++) af[mi] = ldfrag(&As[(wm + mi * 16 + l15) * 32 + quad * 8]);
#pragma unroll
    for (int ni = 0; ni < 4; ni++) bf[ni] = ldfrag(&Bs[(wn + ni * 16 + l15) * 32 + quad * 8]);
#pragma unroll
    for (int mi = 0; mi < 4; mi++)
#pragma unroll
      for (int ni = 0; ni < 4; ni++)
        acc[mi][ni] = MFMA_BF16(af[mi], bf[ni], acc[mi][ni]);
  }
  int sec = n0 >> 10;  // uniform per block: 0=q 1=k 2=v
#pragma unroll
  for (int mi = 0; mi < 4; mi++) {
    int rowb = m0 + wm + mi * 16 + quad * 4;
#pragma unroll
    for (int ni = 0; ni < 4; ni++) {
      int col = n0 + wn + ni * 16 + l15;
      int cc = col & 1023, h = cc >> 6, d = cc & 63;
#pragma unroll
      for (int r = 0; r < 4; r++) {
        int rg = rowb + r, b = rg >> 12, s = rg & 4095;
        u16 v = f2bf(acc[mi][ni][r]);
        size_t bh = (size_t)(b * 16 + h);
        if (sec == 0)      Q [(bh * 4096 + s) * 64 + d] = v;
        else if (sec == 1) Kb[(bh * 4096 + s) * 64 + d] = v;
        else               Vt[(bh * 64 + d) * 4096 + s] = v;
      }
    }
  }
}

// ---------------- RMSNorm + RoPE, in place, 16 lanes x 4 elems per row -------
__global__ __launch_bounds__(256) void k_rms_rope(u16* __restrict__ buf,
                                                  const float* __restrict__ gamma,
                                                  const float* __restrict__ cosb,
                                                  const float* __restrict__ sinb,
                                                  float scale) {
  int rid = blockIdx.x * 16 + (threadIdx.x >> 4);  // row over B*NH*S
  int l = threadIdx.x & 15;                        // 4 elems per lane
  int s = rid & 4095;
  int d0 = l * 4;
  size_t idx = (size_t)rid * 64 + d0;
  u16x4 xv = *(const u16x4*)(buf + idx);
  float x0 = bf2f(xv.x), x1 = bf2f(xv.y), x2 = bf2f(xv.z), x3 = bf2f(xv.w);
  float ss = x0 * x0 + x1 * x1 + x2 * x2 + x3 * x3;
#pragma unroll
  for (int off = 1; off < 16; off <<= 1) ss += __shfl_xor(ss, off);
  float rms = rsqrtf(ss * (1.0f / 64.0f) + 1e-6f);
  float4 g = *(const float4*)(gamma + d0);
  float n0 = x0 * rms * g.x, n1 = x1 * rms * g.y, n2 = x2 * rms * g.z, n3 = x3 * rms * g.w;
  float p0 = __shfl_xor(n0, 8), p1 = __shfl_xor(n1, 8);
  float p2 = __shfl_xor(n2, 8), p3 = __shfl_xor(n3, 8);
  float sgn = (l < 8) ? -1.f : 1.f;
  float4 c = *(const float4*)(cosb + s * 64 + d0);
  float4 sn = *(const float4*)(sinb + s * 64 + d0);
  u16x4 o;
  o.x = f2bf((n0 * c.x + sgn * p0 * sn.x) * scale);
  o.y = f2bf((n1 * c.y + sgn * p1 * sn.y) * scale);
  o.z = f2bf((n2 * c.z + sgn * p2 * sn.z) * scale);
  o.w = f2bf((n3 * c.w + sgn * p3 * sn.w) * scale);
  *(u16x4*)(buf + idx) = o;
}

// ---------------- causal flash attention -----------------------------------
// Q,K: [bh][s][d] bf16 ; Vt: [bh][d][s] bf16 ; out: [b][s][h*64+d] bf16
// Two q-tiles per block (31-t then t) -> every block = exactly 33 k-iters.
// K double-buffered (prefetch issued at iter top); V staged early, read after
// mid barrier; P wave-private 32-col chunks (no barrier). LDS 59.4 KB.
__device__ __forceinline__ void stage_k(const u16* Kg0, int kj, u16* Kbuf,
                                        int wave, int klr, int klc) {
  const u16* Kg = Kg0 + (size_t)kj * 128 * 64;
#pragma unroll
  for (int i = 0; i < 4; i++) {
    int c = wave * 4 + i;
    gload_lds16(Kg + (size_t)(c * 8 + klr) * 64 + (klc ^ klr) * 8, Kbuf + c * 512);
  }
}
__device__ __forceinline__ void stage_v(const u16* Vg0, int kj, u16* Vbuf,
                                        int wave, int quad, int l15) {
  const u16* Vg = Vg0 + kj * 128;
#pragma unroll
  for (int i = 0; i < 4; i++) {
    int c = wave * 4 + i;
    int vr = c * 4 + quad;
    gload_lds16(Vg + (size_t)vr * 4096 + (l15 ^ (vr & 15)) * 8, Vbuf + c * 512);
  }
}

__global__ __launch_bounds__(256) void k_attn(const u16* __restrict__ Qb,
                                              const u16* __restrict__ Kg_all,
                                              const u16* __restrict__ Vtb,
                                              u16* __restrict__ Ob) {
  __shared__ u16 Ks[2][128 * 64];   // 32 KB (double buffer)
  __shared__ u16 Vts[64 * 128];     // 16 KB
  __shared__ u16 Ps[4][32 * 40];    // 10 KB, wave-private, stride 40
  const int PSTR = 40;
  int t = blockIdx.x, bhi = blockIdx.y;
  int tid = threadIdx.x, wave = tid >> 6, lane = tid & 63, quad = lane >> 4, l15 = lane & 15;
  const u16* Kg0 = Kg_all + (size_t)bhi * 4096 * 64;
  const u16* Vg0 = Vtb + (size_t)bhi * 64 * 4096;
  u16* Pw = Ps[wave];
  int klr = lane >> 3, klc = lane & 7;
  int b = bhi >> 4, h = bhi & 15;

#pragma unroll 1
  for (int tt = 0; tt < 2; tt++) {
    int qi = (tt == 0) ? (31 - t) : t;
    const u16* Qg = Qb + ((size_t)bhi * 4096 + qi * 128) * 64;
    bf16x8 aq[2][2];
#pragma unroll
    for (int mi = 0; mi < 2; mi++)
#pragma unroll
      for (int ks = 0; ks < 2; ks++)
        aq[mi][ks] = ldfrag(Qg + (size_t)(wave * 32 + mi * 16 + l15) * 64 + ks * 32 + quad * 8);
    f32x4 oacc[2][4] = {};
    float mrow[2][4], lrow[2][4];
#pragma unroll
    for (int mi = 0; mi < 2; mi++)
#pragma unroll
      for (int r = 0; r < 4; r++) { mrow[mi][r] = -1e30f; lrow[mi][r] = 0.f; }

    if (tt) __syncthreads();          // protect buffers from prev tile readers
    stage_k(Kg0, 0, Ks[0], wave, klr, klc);

#pragma unroll 1
    for (int kj = 0; kj <= qi; kj++) {
      int cur = kj & 1;
      __syncthreads();                // B1: drains prev-iter K prefetch (old)
      if (kj < qi) stage_k(Kg0, kj + 1, Ks[cur ^ 1], wave, klr, klc);
      stage_v(Vg0, kj, Vts, wave, quad, l15);
      // S = Q K^T (q pre-scaled by log2e/8 -> base-2 domain)
      f32x4 sa[2][8] = {};
#pragma unroll
      for (int ks = 0; ks < 2; ks++) {
#pragma unroll
        for (int nb = 0; nb < 8; nb++) {
          bf16x8 bk = ldfrag(&Ks[cur][(nb * 16 + l15) * 64 + (((ks * 4 + quad) ^ (l15 & 7)) << 3)]);
#pragma unroll
          for (int mi = 0; mi < 2; mi++)
            sa[mi][nb] = MFMA_BF16(aq[mi][ks], bk, sa[mi][nb]);
        }
      }
      if (kj == qi) {  // causal mask on diagonal tile (local coords)
#pragma unroll
        for (int mi = 0; mi < 2; mi++)
#pragma unroll
          for (int nb = 0; nb < 8; nb++)
#pragma unroll
            for (int r = 0; r < 4; r++) {
              int rowi = wave * 32 + mi * 16 + quad * 4 + r;
              int coli = nb * 16 + l15;
              if (coli > rowi) sa[mi][nb][r] = -1e30f;
            }
      }
      // online softmax (base-2); overwrite sa with p
#pragma unroll
      for (int mi = 0; mi < 2; mi++) {
#pragma unroll
        for (int r = 0; r < 4; r++) {
          float mx = sa[mi][0][r];
#pragma unroll
          for (int nb = 1; nb < 8; nb++) mx = fmaxf(mx, sa[mi][nb][r]);
#pragma unroll
          for (int off = 1; off < 16; off <<= 1) mx = fmaxf(mx, __shfl_xor(mx, off));
          float mnew = fmaxf(mrow[mi][r], mx);
          float alpha = fexp2(mrow[mi][r] - mnew);
          mrow[mi][r] = mnew;
          float rsum = 0.f;
#pragma unroll
          for (int nb = 0; nb < 8; nb++) {
            float p = fexp2(sa[mi][nb][r] - mnew);
            sa[mi][nb][r] = p;
            rsum += p;
          }
#pragma unroll
          for (int off = 1; off < 16; off <<= 1) rsum += __shfl_xor(rsum, off);
          lrow[mi][r] = lrow[mi][r] * alpha + rsum;
#pragma unroll
          for (int oni = 0; oni < 4; oni++) oacc[mi][oni][r] *= alpha;
        }
      }
      __syncthreads();                // B2: V staged this iter now visible
      // O += P V, 32-wide k chunks; P via wave-private LDS (no barrier)
#pragma unroll
      for (int ks = 0; ks < 4; ks++) {
#pragma unroll
        for (int mi = 0; mi < 2; mi++)
#pragma unroll
          for (int r = 0; r < 4; r++) {
            int prow = mi * 16 + quad * 4 + r;
            Pw[prow * PSTR + l15]      = f2bf(sa[mi][2 * ks][r]);
            Pw[prow * PSTR + 16 + l15] = f2bf(sa[mi][2 * ks + 1][r]);
          }
        bf16x8 ap[2];
#pragma unroll
        for (int mi = 0; mi < 2; mi++)
          ap[mi] = ldfrag(&Pw[(mi * 16 + l15) * PSTR + quad * 8]);
#pragma unroll
        for (int oni = 0; oni < 4; oni++) {
          bf16x8 bv = ldfrag(&Vts[(oni * 16 + l15) * 128 + (((ks * 4 + quad) ^ l15) << 3)]);
#pragma unroll
          for (int mi = 0; mi < 2; mi++)
            oacc[mi][oni] = MFMA_BF16(ap[mi], bv, oacc[mi][oni]);
        }
      }
    }
    // epilogue: O tile to global
#pragma unroll
    for (int mi = 0; mi < 2; mi++)
#pragma unroll
      for (int oni = 0; oni < 4; oni++)
#pragma unroll
        for (int r = 0; r < 4; r++) {
          float v = oacc[mi][oni][r] / lrow[mi][r];
          int srow = qi * 128 + wave * 32 + mi * 16 + quad * 4 + r;
          int d = oni * 16 + l15;
          Ob[((size_t)(b * 4096 + srow)) * 1024 + h * 64 + d] = f2bf(v);
        }
  }
}

// ---------------- out GEMM: A(8192x1024) @ Wot(1024x1024)^T -> fp32 ----------
__global__ __launch_bounds__(256) void k_gemm_out(const u16* __restrict__ A,
                                                  const u16* __restrict__ Bt,
                                                  float* __restrict__ C) {
  const int K = 1024, N = 1024;
  __shared__ u16 As[128 * 32];
  __shared__ u16 Bs[128 * 32];
  int tid = threadIdx.x;
  int wave = tid >> 6, lane = tid & 63, quad = lane >> 4, l15 = lane & 15;
  int m0 = blockIdx.y * 128, n0 = blockIdx.x * 128;
  int wm = (wave >> 1) * 64, wn = (wave & 1) * 64;
  f32x4 acc[4][4] = {};
  const u16* Ag = A + (size_t)m0 * K;
  const u16* Bg = Bt + (size_t)n0 * K;
  int lr = lane >> 2, lk = (lane & 3) * 8;

  for (int k0 = 0; k0 < K; k0 += 32) {
    __syncthreads();
#pragma unroll
    for (int i = 0; i < 2; i++) {
      int c = wave * 2 + i;
      gload_lds16(Ag + (size_t)(c * 16 + lr) * K + k0 + lk, &As[c * 512]);
      gload_lds16(Bg + (size_t)(c * 16 + lr) * K + k0 + lk, &Bs[c * 512]);
    }
    __syncthreads();
    bf16x8 af[4], bf[4];
#pragma unroll
    for (int mi = 0; mi < 4; mi++) af[mi] = ldfrag(&As[(wm + mi * 16 + l15) * 32 + quad * 8]);
#pragma unroll
    for (int ni = 0; ni < 4; ni++) bf[ni] = ldfrag(&Bs[(wn + ni * 16 + l15) * 32 + quad * 8]);
#pragma unroll
    for (int mi = 0; mi < 4; mi++)
#pragma unroll
      for (int ni = 0; ni < 4; ni++)
        acc[mi][ni] = MFMA_BF16(af[mi], bf[ni], acc[mi][ni]);
  }
#pragma unroll
  for (int mi = 0; mi < 4; mi++) {
    int rowb = m0 + wm + mi * 16 + quad * 4;
#pragma unroll
    for (int ni = 0; ni < 4; ni++) {
      int col = n0 + wn + ni * 16 + l15;
#pragma unroll
      for (int r = 0; r < 4; r++)
        C[(size_t)(rowb + r) * N + col] = acc[mi][ni][r];
    }
  }
}

extern "C" void kernel_launch(void* const* d_in, const int* in_sizes, int n_in,
                              void* d_out, int out_size, void* d_ws, size_t ws_size,
                              hipStream_t stream) {
  (void)in_sizes; (void)n_in; (void)out_size; (void)ws_size;
  const float* hs   = (const float*)d_in[0];  // (2,4096,1024)
  const float* cosb = (const float*)d_in[1];  // (1,4096,64)
  const float* sinb = (const float*)d_in[2];
  const float* wqkv = (const float*)d_in[3];  // (1024,3072)
  const float* wo   = (const float*)d_in[4];  // (1024,1024)
  const float* gq   = (const float*)d_in[5];
  const float* gk   = (const float*)d_in[6];
  float* out = (float*)d_out;

  char* ws = (char*)d_ws;
  u16* Xb    = (u16*)(ws);              // 16,777,216 B
  u16* Wqkvt = (u16*)(ws + 16777216);   //  6,291,456 B
  u16* Wot   = (u16*)(ws + 23068672);   //  2,097,152 B
  u16* Qb    = (u16*)(ws + 25165824);   // 16,777,216 B
  u16* Kb    = (u16*)(ws + 41943040);   // 16,777,216 B
  u16* Vtb   = (u16*)(ws + 58720256);   // 16,777,216 B
  u16* Ab    = (u16*)(ws + 75497472);   // 16,777,216 B  (total ~92.3 MB)

  k_f32_to_bf16<<<8192, 256, 0, stream>>>(hs, Xb, 8388608);
  k_transpose_bf16<<<dim3(96, 32), dim3(32, 8), 0, stream>>>(wqkv, Wqkvt, 1024, 3072);
  k_transpose_bf16<<<dim3(32, 32), dim3(32, 8), 0, stream>>>(wo, Wot, 1024, 1024);
  k_gemm_qkv<<<dim3(24, 64), 256, 0, stream>>>(Xb, Wqkvt, Qb, Kb, Vtb);
  // Q scaled by 1/sqrt(hd) * log2(e): softmax runs in base-2 domain
  k_rms_rope<<<8192, 256, 0, stream>>>(Qb, gq, cosb, sinb, 0.18033688011112042f);
  k_rms_rope<<<8192, 256, 0, stream>>>(Kb, gk, cosb, sinb, 1.0f);
  k_attn<<<dim3(16, 32), 256, 0, stream>>>(Qb, Kb, Vtb, Ab);
  k_gemm_out<<<dim3(8, 64), 256, 0, stream>>>(Ab, Wot, out);
}